// Round 3
// baseline (145.350 us; speedup 1.0000x reference)
//
#include <hip/hip_runtime.h>
#include <hip/hip_bf16.h>

// Problem: per batch b, out[b] = (X[b] (512x4096) · K_in[b] (4096x8)) · K_out[b] (8x4096)
//   K_in / K_out composed from gate-merged TT cores (tiny compute).
// V-phase reads X global->register with line-coalesced fragment mapping
// (wave = 16 rows x 64B), K_in pre-packed bf16 [m][p0..7] (16B/m, L2-hot).

#define MC_ 16            // m-slices of 256 for the V reduction

__global__ __launch_bounds__(256) void k_compose(
    const float* __restrict__ gates,
    const float* __restrict__ core_first,
    const float* __restrict__ cores_mid,
    const float* __restrict__ core_last,
    __hip_bfloat16* __restrict__ Kinb,   // [8][4096][8] bf16
    float* __restrict__ Kout)            // [8][8][4096] f32
{
  const int part = blockIdx.x;   // 0..7 : m3 slice for Kin, n0 slice for Kout
  const int b    = blockIdx.y;
  const int t    = threadIdx.x;

  __shared__ float g[8];
  __shared__ float mg[3200];                     // merged cores
  __shared__ __align__(16) float A2[512];        // [(m1,m0)][p2]
  __shared__ __align__(16) float A3[4096];       // [(m2,m1,m0)][p3]
  __shared__ __align__(16) float C2[512];        // [p6][(n2,n3)]
  __shared__ __align__(16) float C3[4096];       // [p5][(n1,n2,n3)]

  if (t < 8) g[t] = gates[b*8 + t];
  __syncthreads();

  for (int idx = t; idx < 3200; idx += 256) {
    float acc = 0.f;
    if (idx < 64) {
      #pragma unroll
      for (int e = 0; e < 8; ++e) acc += g[e] * core_first[e*64 + idx];
    } else if (idx < 3136) {
      const int i = (idx - 64) >> 9;
      const int w = (idx - 64) & 511;
      #pragma unroll
      for (int e = 0; e < 8; ++e) acc += g[e] * cores_mid[(i*8 + e)*512 + w];
    } else {
      const int w = idx - 3136;
      #pragma unroll
      for (int e = 0; e < 8; ++e) acc += g[e] * core_last[e*64 + w];
    }
    mg[idx] = acc;
  }
  __syncthreads();

  const float* mg0 = mg;
  const float* mg1 = mg + 64;
  const float* mg2 = mg + 64 + 512;
  const float* mg3 = mg + 64 + 1024;
  const float* mg4 = mg + 64 + 1536;
  const float* mg5 = mg + 64 + 2048;
  const float* mg6 = mg + 64 + 2560;
  const float* mg7 = mg + 3136;

  for (int idx = t; idx < 1024; idx += 256) {
    if (idx < 512) {
      const int mm = idx >> 3, p2 = idx & 7;
      const int m1 = mm >> 3, m0 = mm & 7;
      float acc = 0.f;
      #pragma unroll
      for (int p1 = 0; p1 < 8; ++p1)
        acc += mg0[m0*8 + p1] * mg1[p1*64 + m1*8 + p2];
      A2[idx] = acc;
    } else {
      const int id = idx - 512;
      const int p6 = id >> 6, n2 = (id >> 3) & 7, n3 = id & 7;
      float acc = 0.f;
      #pragma unroll
      for (int p7 = 0; p7 < 8; ++p7)
        acc += mg6[p6*64 + n2*8 + p7] * mg7[p7*8 + n3];
      C2[id] = acc;
    }
  }
  __syncthreads();

  for (int idx = t; idx < 8192; idx += 256) {
    if (idx < 4096) {
      const int rest = idx >> 3, p3 = idx & 7;
      const int m2 = rest >> 6, mm = rest & 63;
      float acc = 0.f;
      #pragma unroll
      for (int p2 = 0; p2 < 8; ++p2)
        acc += A2[mm*8 + p2] * mg2[p2*64 + m2*8 + p3];
      A3[idx] = acc;
    } else {
      const int id = idx - 4096;
      const int p5 = id >> 9, n1 = (id >> 6) & 7, nn = id & 63;
      float acc = 0.f;
      #pragma unroll
      for (int p6 = 0; p6 < 8; ++p6)
        acc += mg5[p5*64 + n1*8 + p6] * C2[p6*64 + nn];
      C3[id] = acc;
    }
  }
  __syncthreads();

  {
    __hip_bfloat16* kb = Kinb + ((size_t)b*4096 + part*512)*8;
    #pragma unroll
    for (int rr = 0; rr < 2; ++rr) {
      const int r = t*2 + rr;
      #pragma unroll
      for (int p4 = 0; p4 < 8; ++p4) {
        float acc = 0.f;
        #pragma unroll
        for (int p3 = 0; p3 < 8; ++p3)
          acc += A3[r*8 + p3] * mg3[p3*64 + part*8 + p4];
        kb[r*8 + p4] = __float2bfloat16(acc);
      }
    }
    float* ob = Kout + b*32768 + part*512;
    #pragma unroll
    for (int jj = 0; jj < 2; ++jj) {
      const int j = t*2 + jj;
      #pragma unroll
      for (int p4 = 0; p4 < 8; ++p4) {
        float acc = 0.f;
        #pragma unroll
        for (int p5 = 0; p5 < 8; ++p5)
          acc += mg4[p4*64 + part*8 + p5] * C3[p5*512 + j];
        ob[p4*4096 + j] = acc;
      }
    }
  }
}

__device__ __forceinline__ float bfhi(unsigned u) {
  return __uint_as_float(u & 0xffff0000u);
}
__device__ __forceinline__ float bflo(unsigned u) {
  return __uint_as_float(u << 16);
}

// V partials, no LDS. Wave = 16 rows x 4 quads; per instr the wave reads
// 16 full 64B lines of X (global->register). K_in bf16 [m][p] broadcast from L2.
// Vpart[b][mc][s][p] = sum_{m in slice mc (256)} X[b][s][m] * Kin[b][m][p]
__global__ __launch_bounds__(256) void k_vpart(
    const float* __restrict__ X,
    const uint4* __restrict__ Kinb,     // [8*4096] x (8 bf16 = 16B per m)
    float* __restrict__ Vpart)
{
  const int sg = blockIdx.x;   // 0..7  (64 rows each)
  const int mc = blockIdx.y;   // 0..15 (256 m each)
  const int b  = blockIdx.z;   // 0..7
  const int t  = threadIdx.x;

  const int w = t >> 6;        // wave 0..3
  const int l = t & 63;
  const int r = l & 15;        // row within wave-tile
  const int q = l >> 4;        // quad 0..3

  const int row = sg*64 + w*16 + r;
  const float* xr = X + ((size_t)(b*512 + row))*4096 + mc*256 + q*4;
  const uint4* kr = Kinb + (size_t)b*4096 + mc*256 + q*4;

  float acc[8];
  #pragma unroll
  for (int p = 0; p < 8; ++p) acc[p] = 0.f;

  #pragma unroll 4
  for (int j = 0; j < 16; ++j) {
    const float4 x4 = *(const float4*)(xr + j*16);
    const float xv[4] = {x4.x, x4.y, x4.z, x4.w};
    #pragma unroll
    for (int i = 0; i < 4; ++i) {
      const uint4 k8 = kr[j*16 + i];
      const float xi = xv[i];
      acc[0] += xi * bflo(k8.x);  acc[1] += xi * bfhi(k8.x);
      acc[2] += xi * bflo(k8.y);  acc[3] += xi * bfhi(k8.y);
      acc[4] += xi * bflo(k8.z);  acc[5] += xi * bfhi(k8.z);
      acc[6] += xi * bflo(k8.w);  acc[7] += xi * bfhi(k8.w);
    }
  }

  // Reduce across the 4 quads (lane bits 4,5).
  #pragma unroll
  for (int p = 0; p < 8; ++p) {
    acc[p] += __shfl_xor(acc[p], 16, 64);
    acc[p] += __shfl_xor(acc[p], 32, 64);
  }

  if (l < 16) {
    float* vp = Vpart + ((size_t)((b*MC_ + mc)*512) + row)*8;
    *(float4*)(vp)     = make_float4(acc[0], acc[1], acc[2], acc[3]);
    *(float4*)(vp + 4) = make_float4(acc[4], acc[5], acc[6], acc[7]);
  }
}

// out[b][s][n] = sum_p (sum_mc Vpart[b][mc][s][p]) * Kout[b][p][n]
__global__ __launch_bounds__(256) void k_out(
    const float* __restrict__ Vpart,
    const float* __restrict__ Kout,
    float* __restrict__ Out)
{
  const int nc = blockIdx.x;   // 0..3   (1024 n each)
  const int sg = blockIdx.y;   // 0..15  (32 s each)
  const int b  = blockIdx.z;   // 0..7
  const int t  = threadIdx.x;

  __shared__ __align__(16) float vs[32*8];

  // Sum the MC_ m-slice partials for this block's 32 s.  t == s_local*8 + p.
  {
    const float* vp = Vpart + ((size_t)b*MC_*512 + sg*32)*8 + t;
    float a = 0.f;
    #pragma unroll
    for (int mc = 0; mc < MC_; ++mc) a += vp[(size_t)mc*512*8];
    vs[t] = a;
  }

  float4 kr[8];
  {
    const float* kb = Kout + b*32768 + nc*1024 + t*4;
    #pragma unroll
    for (int p = 0; p < 8; ++p) kr[p] = *(const float4*)(kb + p*4096);
  }
  __syncthreads();

  float* ob = Out + (size_t)(b*512 + sg*32)*4096 + nc*1024 + t*4;
  for (int s = 0; s < 32; ++s) {
    const float* vv = &vs[s*8];
    float o0 = 0.f, o1 = 0.f, o2 = 0.f, o3 = 0.f;
    #pragma unroll
    for (int p = 0; p < 8; ++p) {
      const float v = vv[p];
      o0 += v * kr[p].x; o1 += v * kr[p].y; o2 += v * kr[p].z; o3 += v * kr[p].w;
    }
    *(float4*)(ob + (size_t)s*4096) = make_float4(o0, o1, o2, o3);
  }
}

extern "C" void kernel_launch(void* const* d_in, const int* in_sizes, int n_in,
                              void* d_out, int out_size, void* d_ws, size_t ws_size,
                              hipStream_t stream) {
  const float* X     = (const float*)d_in[0];
  const float* gates = (const float*)d_in[1];
  const float* cf    = (const float*)d_in[2];
  const float* cm    = (const float*)d_in[3];
  const float* cl    = (const float*)d_in[4];
  float* out = (float*)d_out;

  float* ws = (float*)d_ws;
  float*          Kout  = ws;                          // 262144 f (1 MB)
  float*          Vpart = ws + 262144;                 // MC_*512*8*8 = 524288 f (2 MB)
  __hip_bfloat16* Kinb  = (__hip_bfloat16*)(ws + 262144 + 524288);  // 512 KB

  k_compose<<<dim3(8, 8),        256, 0, stream>>>(gates, cf, cm, cl, Kinb, Kout);
  k_vpart <<<dim3(8, MC_, 8),    256, 0, stream>>>(X, (const uint4*)Kinb, Vpart);
  k_out   <<<dim3(4, 16, 8),     256, 0, stream>>>(Vpart, Kout, out);
}